// Round 3
// baseline (5564.882 us; speedup 1.0000x reference)
//
#include <hip/hip_runtime.h>
#include <stdint.h>

#define CDIM   256
#define KCODES 1024
#define HWSZ   4096
#define NROWS  131072
#define DELTA  4e-4f

// workspace layout (bytes)
#define WS_A     0          // 512 KB fp32 A[n]
#define WS_BQ    524288     // 4 KB   fp32 Bq[k]
#define WS_IDX   528384     // 512 KB int   idx[n]
#define WS_CBBF  1052672    // 512 KB bf16  cbbf[k][c]
#define WS_CNT   1576960    // 4 B (padded 128) flagged count
#define WS_LIST  1577088    // 512 KB int flagged row list

typedef __attribute__((ext_vector_type(8))) short short8;
typedef __attribute__((ext_vector_type(4))) float f32x4;

__device__ inline unsigned short bf16rne(float f) {
    uint32_t u = __float_as_uint(f);
    u += 0x7FFF + ((u >> 16) & 1);
    return (unsigned short)(u >> 16);
}

__device__ inline void async16(const void* g, void* l) {
    __builtin_amdgcn_global_load_lds(
        (const __attribute__((address_space(1))) unsigned int*)g,
        (__attribute__((address_space(3))) unsigned int*)l, 16, 0, 0);
}

// ---------- A[n] = np.sum(x_row^2), numpy pairwise tree (verified r2) ----------
__global__ void rowsq_kernel(const float* __restrict__ x, float* __restrict__ A) {
#pragma clang fp contract(off)
    int n = blockIdx.x * 256 + threadIdx.x;
    const float* xr = x + (size_t)(n >> 12) * (CDIM * HWSZ) + (n & 4095);
    float half_s[2];
    for (int h = 0; h < 2; ++h) {
        float r[8];
        #pragma unroll
        for (int j = 0; j < 8; ++j) { float v = xr[(size_t)(h*128 + j) * HWSZ]; r[j] = v * v; }
        for (int i = 8; i < 128; i += 8) {
            #pragma unroll
            for (int j = 0; j < 8; ++j) {
                float v = xr[(size_t)(h*128 + i + j) * HWSZ];
                float sq = v * v;
                r[j] = r[j] + sq;
            }
        }
        half_s[h] = ((r[0]+r[1]) + (r[2]+r[3])) + ((r[4]+r[5]) + (r[6]+r[7]));
    }
    A[n] = half_s[0] + half_s[1];
}

// ---------- Bq[k] = np.sum(cb_row^2), numpy tree (verified r2) ----------
__global__ void codesq_kernel(const float* __restrict__ cb, float* __restrict__ Bq) {
#pragma clang fp contract(off)
    int k = blockIdx.x * 256 + threadIdx.x;
    if (k >= KCODES) return;
    const float* er = cb + (size_t)k * CDIM;
    float half_s[2];
    for (int h = 0; h < 2; ++h) {
        float r[8];
        #pragma unroll
        for (int j = 0; j < 8; ++j) { float v = er[h*128 + j]; r[j] = v * v; }
        for (int i = 8; i < 128; i += 8) {
            #pragma unroll
            for (int j = 0; j < 8; ++j) { float v = er[h*128 + i + j]; float sq = v*v; r[j] = r[j] + sq; }
        }
        half_s[h] = ((r[0]+r[1]) + (r[2]+r[3])) + ((r[4]+r[5]) + (r[6]+r[7]));
    }
    Bq[k] = half_s[0] + half_s[1];
}

// ---------- cb fp32 -> bf16 (+ zero flag counter) ----------
__global__ void cbcvt_kernel(const float* __restrict__ cb, unsigned short* __restrict__ cbbf,
                             int* __restrict__ counter) {
    int i = blockIdx.x * 256 + threadIdx.x;      // 65536 float4 groups
    float4 v = ((const float4*)cb)[i];
    ushort4 o;
    o.x = bf16rne(v.x); o.y = bf16rne(v.y); o.z = bf16rne(v.z); o.w = bf16rne(v.w);
    ((ushort4*)cbbf)[i] = o;
    if (i == 0) *counter = 0;
}

// ---------- MFMA bf16 screen: per-row top2 of (|e|^2 - 2 x.e) over all K ----------
__global__ __launch_bounds__(256)
void screen_kernel(const float* __restrict__ x, const unsigned short* __restrict__ cbbf,
                   const float* __restrict__ Bq,
                   int* __restrict__ idx_out, float* __restrict__ outF,
                   int* __restrict__ flag_list, int* __restrict__ counter) {
    __shared__ unsigned short xs[64 * 264];      // [row][c], pad 256->264
    __shared__ unsigned short Bbuf[8192];        // 128 k x 64 c, 16B-slot XOR swizzle
    __shared__ float sRed[2][64][4];

    const int t = threadIdx.x;
    const int w = t >> 6, l = t & 63;
    const int l15 = l & 15, quad = l >> 4;
    const int wr = w & 1, wc = w >> 1;
    const int r0 = blockIdx.x * 64;
    const float* xbase = x + (size_t)(r0 >> 12) * (CDIM * HWSZ) + (r0 & 4095);

    // ---- stage x tile: fp32 [c][row] global -> bf16 [row][c] LDS (once) ----
    {
        int cbase = (t >> 4) * 2;
        int row4  = (t & 15) * 4;
        for (int it = 0; it < 8; ++it) {
            int c = cbase + it * 32;
            float4 fa = *(const float4*)(xbase + (size_t)c * HWSZ + row4);
            float4 fb = *(const float4*)(xbase + (size_t)(c + 1) * HWSZ + row4);
            *(uint32_t*)&xs[(row4+0)*264 + c] = (uint32_t)bf16rne(fa.x) | ((uint32_t)bf16rne(fb.x) << 16);
            *(uint32_t*)&xs[(row4+1)*264 + c] = (uint32_t)bf16rne(fa.y) | ((uint32_t)bf16rne(fb.y) << 16);
            *(uint32_t*)&xs[(row4+2)*264 + c] = (uint32_t)bf16rne(fa.z) | ((uint32_t)bf16rne(fb.z) << 16);
            *(uint32_t*)&xs[(row4+3)*264 + c] = (uint32_t)bf16rne(fa.w) | ((uint32_t)bf16rne(fb.w) << 16);
        }
    }

    float v1[8], v2[8]; int k1[8], k2[8];
    #pragma unroll
    for (int i = 0; i < 8; ++i) { v1[i] = 3.4e38f; v2[i] = 3.4e38f; k1[i] = 0; k2[i] = 0; }

    for (int kt = 0; kt < 8; ++kt) {
        f32x4 acc[2][4];
        #pragma unroll
        for (int rf = 0; rf < 2; ++rf)
            #pragma unroll
            for (int cf = 0; cf < 4; ++cf) acc[rf][cf] = (f32x4){0.f, 0.f, 0.f, 0.f};

        for (int cc = 0; cc < 4; ++cc) {
            __syncthreads();                      // prev compute done; Bbuf reusable
            // stage B chunk: 128 k x 64 c bf16 via global_load_lds (16B, swizzled)
            {
                const unsigned short* gk = cbbf + (size_t)kt * 128 * 256 + cc * 64;
                #pragma unroll
                for (int i = 0; i < 4; ++i) {
                    int slot = w * 256 + i * 64 + l;
                    int k = slot >> 3, g = l & 7;
                    async16((const void*)(gk + (size_t)k * 256 + ((g ^ (k & 7)) * 8)),
                            (void*)(Bbuf + slot * 8));
                }
            }
            __syncthreads();                      // drains vmcnt -> Bbuf visible
            #pragma unroll
            for (int s = 0; s < 2; ++s) {
                short8 af[2];
                #pragma unroll
                for (int rf = 0; rf < 2; ++rf)
                    af[rf] = *(const short8*)&xs[(wr*32 + rf*16 + l15)*264 + cc*64 + s*32 + quad*8];
                short8 bfr[4];
                #pragma unroll
                for (int cf = 0; cf < 4; ++cf) {
                    int kl = cf*16 + l15;
                    int g  = s*4 + quad;
                    int slot = kl*8 + (g ^ (kl & 7));
                    bfr[cf] = *(const short8*)&Bbuf[slot * 8];
                }
                #pragma unroll
                for (int rf = 0; rf < 2; ++rf)
                    #pragma unroll
                    for (int cf = 0; cf < 4; ++cf)
                        acc[rf][cf] = __builtin_amdgcn_mfma_f32_16x16x32_bf16(
                            af[rf], bfr[cf], acc[rf][cf], 0, 0, 0);
            }
        }

        // epilogue: s = Bq[k] - 2*dot ; running top2 per row
        float bqv[4];
        #pragma unroll
        for (int cf = 0; cf < 4; ++cf) bqv[cf] = Bq[kt*128 + wc*64 + cf*16 + l15];
        #pragma unroll
        for (int rf = 0; rf < 2; ++rf)
            #pragma unroll
            for (int reg = 0; reg < 4; ++reg) {
                int st = rf*4 + reg;
                #pragma unroll
                for (int cf = 0; cf < 4; ++cf) {
                    float s = fmaf(-2.f, acc[rf][cf][reg], bqv[cf]);
                    int kk = kt*128 + wc*64 + cf*16 + l15;
                    bool lt1 = s < v1[st];
                    bool lt2 = s < v2[st];
                    v2[st] = lt1 ? v1[st] : (lt2 ? s : v2[st]);
                    k2[st] = lt1 ? k1[st] : (lt2 ? kk : k2[st]);
                    v1[st] = lt1 ? s : v1[st];
                    k1[st] = lt1 ? kk : k1[st];
                }
            }
    }

    // butterfly merge across the 16 lanes sharing each row set
    #pragma unroll
    for (int st = 0; st < 8; ++st) {
        #pragma unroll
        for (int m = 1; m < 16; m <<= 1) {
            float ov1 = __shfl_xor(v1[st], m, 64); int on1 = __shfl_xor(k1[st], m, 64);
            float ov2 = __shfl_xor(v2[st], m, 64); int on2 = __shfl_xor(k2[st], m, 64);
            bool sw = (ov1 < v1[st]) || (ov1 == v1[st] && on1 < k1[st]);
            float wv1 = sw ? ov1 : v1[st]; int wk1 = sw ? on1 : k1[st];
            float wv2 = sw ? ov2 : v2[st]; int wk2 = sw ? on2 : k2[st];
            float lv1 = sw ? v1[st] : ov1; int lk1 = sw ? k1[st] : on1;
            bool s2 = (lv1 < wv2) || (lv1 == wv2 && lk1 < wk2);
            v1[st] = wv1; k1[st] = wk1;
            v2[st] = s2 ? lv1 : wv2;
            k2[st] = s2 ? lk1 : wk2;
        }
    }
    if (l15 == 0) {
        #pragma unroll
        for (int rf = 0; rf < 2; ++rf)
            #pragma unroll
            for (int reg = 0; reg < 4; ++reg) {
                int r = wr*32 + rf*16 + quad*4 + reg;
                int st = rf*4 + reg;
                sRed[wc][r][0] = v1[st];
                sRed[wc][r][1] = __int_as_float(k1[st]);
                sRed[wc][r][2] = v2[st];
                sRed[wc][r][3] = __int_as_float(k2[st]);
            }
    }
    __syncthreads();
    if (t < 64) {
        float a1 = sRed[0][t][0]; int an1 = __float_as_int(sRed[0][t][1]);
        float a2 = sRed[0][t][2]; int an2 = __float_as_int(sRed[0][t][3]);
        float b1 = sRed[1][t][0]; int bn1 = __float_as_int(sRed[1][t][1]);
        float b2 = sRed[1][t][2]; int bn2 = __float_as_int(sRed[1][t][3]);
        bool sw = (b1 < a1) || (b1 == a1 && bn1 < an1);
        float wv1 = sw ? b1 : a1; int wk1 = sw ? bn1 : an1;
        float wv2 = sw ? b2 : a2; int wk2 = sw ? bn2 : an2;
        float lv1 = sw ? a1 : b1; int lk1 = sw ? an1 : bn1;
        bool s2 = (lv1 < wv2) || (lv1 == wv2 && lk1 < wk2);
        float m2 = s2 ? lv1 : wv2;
        int row = r0 + t;
        idx_out[row] = wk1;
        outF[row] = (float)wk1;
        if (m2 - wv1 <= DELTA) {
            int pos = atomicAdd(counter, 1);
            flag_list[pos] = row;
        }
    }
}

// ---------- exact np-fp32 rescore of flagged rows (full 1024-code scan) ----------
__global__ __launch_bounds__(256)
void rescore_kernel(const float* __restrict__ x, const float* __restrict__ cb,
                    const float* __restrict__ A, const float* __restrict__ Bq,
                    const int* __restrict__ flag_list, const int* __restrict__ counter,
                    int* __restrict__ idx_out, float* __restrict__ outF) {
    __shared__ float xsh[8][260];
    __shared__ int   rows_s[8];
    __shared__ float redv[4][8];
    __shared__ int   redk[4][8];

    int cnt = *counter;
    int nbat = (cnt + 7) >> 3;
    for (int bat = blockIdx.x; bat < nbat; bat += gridDim.x) {
        int base = bat * 8;
        __syncthreads();
        if (threadIdx.x < 8) {
            int j = base + threadIdx.x;
            rows_s[threadIdx.x] = (j < cnt) ? flag_list[j] : -1;
        }
        __syncthreads();
        {
            int rr = threadIdx.x >> 5;
            int c0 = (threadIdx.x & 31) * 8;
            int row = rows_s[rr]; if (row < 0) row = rows_s[0];
            const float* xr = x + (size_t)(row >> 12) * (CDIM * HWSZ) + (row & 4095);
            #pragma unroll
            for (int j = 0; j < 8; ++j)
                xsh[rr][c0 + j] = xr[(size_t)(c0 + j) * HWSZ];
        }
        __syncthreads();

        float acc[4][8];
        #pragma unroll
        for (int kk = 0; kk < 4; ++kk)
            #pragma unroll
            for (int r = 0; r < 8; ++r) acc[kk][r] = 0.f;
        const int kb = threadIdx.x * 4;
        for (int c4 = 0; c4 < 64; ++c4) {
            float4 xr4[8];
            #pragma unroll
            for (int r = 0; r < 8; ++r) xr4[r] = *(const float4*)&xsh[r][c4 * 4];
            #pragma unroll
            for (int kk = 0; kk < 4; ++kk) {
                float4 e = *(const float4*)(cb + (size_t)(kb + kk) * CDIM + c4 * 4);
                #pragma unroll
                for (int r = 0; r < 8; ++r) {
                    acc[kk][r] = fmaf(xr4[r].x, e.x, acc[kk][r]);
                    acc[kk][r] = fmaf(xr4[r].y, e.y, acc[kk][r]);
                    acc[kk][r] = fmaf(xr4[r].z, e.z, acc[kk][r]);
                    acc[kk][r] = fmaf(xr4[r].w, e.w, acc[kk][r]);
                }
            }
        }

        float Ar[8];
        #pragma unroll
        for (int r = 0; r < 8; ++r) Ar[r] = (rows_s[r] >= 0) ? A[rows_s[r]] : 0.f;
        float bv[8]; int bk[8];
        #pragma unroll
        for (int r = 0; r < 8; ++r) { bv[r] = 3.4e38f; bk[r] = 0; }
        #pragma unroll
        for (int kk = 0; kk < 4; ++kk) {
            float bq = Bq[kb + kk];
            #pragma unroll
            for (int r = 0; r < 8; ++r) {
                float T1 = Ar[r] + bq;
                float s  = T1 - 2.0f * acc[kk][r];     // same form as r2-verified kernel
                int k = kb + kk;
                if (s < bv[r] || (s == bv[r] && k < bk[r])) { bv[r] = s; bk[r] = k; }
            }
        }
        #pragma unroll
        for (int m = 1; m < 64; m <<= 1)
            #pragma unroll
            for (int r = 0; r < 8; ++r) {
                float ov = __shfl_xor(bv[r], m, 64);
                int   ok = __shfl_xor(bk[r], m, 64);
                if (ov < bv[r] || (ov == bv[r] && ok < bk[r])) { bv[r] = ov; bk[r] = ok; }
            }
        int wv = threadIdx.x >> 6;
        if ((threadIdx.x & 63) == 0)
            #pragma unroll
            for (int r = 0; r < 8; ++r) { redv[wv][r] = bv[r]; redk[wv][r] = bk[r]; }
        __syncthreads();
        if (threadIdx.x < 8) {
            int r = threadIdx.x;
            float best = redv[0][r]; int bbk = redk[0][r];
            #pragma unroll
            for (int ww = 1; ww < 4; ++ww) {
                float ov = redv[ww][r]; int ok = redk[ww][r];
                if (ov < best || (ov == best && ok < bbk)) { best = ov; bbk = ok; }
            }
            int row = rows_s[r];
            if (row >= 0) { idx_out[row] = bbk; outF[row] = (float)bbk; }
        }
    }
}

// ---------- gather codebook rows + NHWC->NCHW transpose (verified r2) ----------
__global__ __launch_bounds__(256)
void gather_kernel(const float* __restrict__ cb, const int* __restrict__ idx,
                   float* __restrict__ out) {
    __shared__ int   sIdx[64];
    __shared__ float tile[64 * 129];
    const int t  = threadIdx.x;
    const int bh = blockIdx.x;
    const int b  = bh >> 6, h = bh & 63;

    if (t < 64) {
        int id = idx[bh * 64 + t];
        sIdx[t] = id;
        out[bh * 64 + t] = (float)id;
    }
    __syncthreads();

    float* qout = out + NROWS + (size_t)b * (CDIM * HWSZ) + h * 64;

    for (int c0 = 0; c0 < CDIM; c0 += 128) {
        if (c0) __syncthreads();
        {
            int ww = t >> 2, seg = t & 3;
            const float* crow = cb + (size_t)sIdx[ww] * CDIM + c0;
            #pragma unroll
            for (int jj = 0; jj < 8; ++jj) {
                int f = seg + 4 * jj;
                float4 v = *(const float4*)(crow + 4 * f);
                float* dst = &tile[ww * 129 + 4 * f];
                dst[0] = v.x; dst[1] = v.y; dst[2] = v.z; dst[3] = v.w;
            }
        }
        __syncthreads();
        {
            int g = t >> 4, w4 = (t & 15) * 4;
            #pragma unroll
            for (int it = 0; it < 8; ++it) {
                int cl = it * 16 + g;
                float4 v;
                v.x = tile[(w4 + 0) * 129 + cl];
                v.y = tile[(w4 + 1) * 129 + cl];
                v.z = tile[(w4 + 2) * 129 + cl];
                v.w = tile[(w4 + 3) * 129 + cl];
                *(float4*)(qout + (size_t)(c0 + cl) * HWSZ + w4) = v;
            }
        }
    }
}

extern "C" void kernel_launch(void* const* d_in, const int* in_sizes, int n_in,
                              void* d_out, int out_size, void* d_ws, size_t ws_size,
                              hipStream_t stream) {
    const float* x  = (const float*)d_in[0];
    const float* cb = (const float*)d_in[1];
    char* ws = (char*)d_ws;
    float*          A     = (float*)(ws + WS_A);
    float*          Bq    = (float*)(ws + WS_BQ);
    int*            idxbf = (int*)(ws + WS_IDX);
    unsigned short* cbbf  = (unsigned short*)(ws + WS_CBBF);
    int*            cnt   = (int*)(ws + WS_CNT);
    int*            list  = (int*)(ws + WS_LIST);
    float*          out   = (float*)d_out;

    rowsq_kernel <<<NROWS / 256, 256, 0, stream>>>(x, A);
    codesq_kernel<<<KCODES / 256, 256, 0, stream>>>(cb, Bq);
    cbcvt_kernel <<<256, 256, 0, stream>>>(cb, cbbf, cnt);
    screen_kernel<<<NROWS / 64, 256, 0, stream>>>(x, cbbf, Bq, idxbf, out, list, cnt);
    rescore_kernel<<<1024, 256, 0, stream>>>(x, cb, A, Bq, list, cnt, idxbf, out);
    gather_kernel<<<32 * 64, 256, 0, stream>>>(cb, idxbf, out);
}

// Round 4
// 778.782 us; speedup vs baseline: 7.1456x; 7.1456x over previous
//
#include <hip/hip_runtime.h>
#include <stdint.h>

#define CDIM   256
#define KCODES 1024
#define HWSZ   4096
#define NROWS  131072
#define DELTA  4e-4f

// workspace layout (bytes)
#define WS_BQ    0          // 4 KB   fp32 Bq[k]
#define WS_IDX   4096       // 512 KB int   idx[n]
#define WS_CBBF  528384     // 512 KB bf16  cbbf[k][c]
#define WS_CNT   1052672    // 4 B (padded 128) flagged count
#define WS_LIST  1052800    // 512 KB int flagged row list

typedef __attribute__((ext_vector_type(8))) short short8;
typedef __attribute__((ext_vector_type(4))) float f32x4;

__device__ inline unsigned short bf16rne(float f) {
    uint32_t u = __float_as_uint(f);
    u += 0x7FFF + ((u >> 16) & 1);
    return (unsigned short)(u >> 16);
}

// ---------- Bq[k] = np.sum(cb_row^2), numpy pairwise tree (verified r2) ----------
__global__ void codesq_kernel(const float* __restrict__ cb, float* __restrict__ Bq) {
#pragma clang fp contract(off)
    int k = blockIdx.x * 256 + threadIdx.x;
    if (k >= KCODES) return;
    const float* er = cb + (size_t)k * CDIM;
    float half_s[2];
    for (int h = 0; h < 2; ++h) {
        float r[8];
        #pragma unroll
        for (int j = 0; j < 8; ++j) { float v = er[h*128 + j]; r[j] = v * v; }
        for (int i = 8; i < 128; i += 8) {
            #pragma unroll
            for (int j = 0; j < 8; ++j) { float v = er[h*128 + i + j]; float sq = v*v; r[j] = r[j] + sq; }
        }
        half_s[h] = ((r[0]+r[1]) + (r[2]+r[3])) + ((r[4]+r[5]) + (r[6]+r[7]));
    }
    Bq[k] = half_s[0] + half_s[1];
}

// ---------- cb fp32 -> bf16 (+ zero flag counter) ----------
__global__ void cbcvt_kernel(const float* __restrict__ cb, unsigned short* __restrict__ cbbf,
                             int* __restrict__ counter) {
    int i = blockIdx.x * 256 + threadIdx.x;      // 65536 float4 groups
    float4 v = ((const float4*)cb)[i];
    ushort4 o;
    o.x = bf16rne(v.x); o.y = bf16rne(v.y); o.z = bf16rne(v.z); o.w = bf16rne(v.w);
    ((ushort4*)cbbf)[i] = o;
    if (i == 0) *counter = 0;
}

// ---------- MFMA bf16 screen: per-row top2 of (|e|^2 - 2 x.e); B direct from global ----------
__global__ __launch_bounds__(256, 2)
void screen_kernel(const float* __restrict__ x, const unsigned short* __restrict__ cbbf,
                   const float* __restrict__ Bq,
                   int* __restrict__ idx_out, float* __restrict__ outF,
                   int* __restrict__ flag_list, int* __restrict__ counter) {
    __shared__ unsigned short xs[64 * 264];      // [row][c], pad 256->264 (A operand)
    __shared__ float sRed[4][64][4];

    const int t = threadIdx.x;
    const int w = t >> 6, l = t & 63;
    const int l15 = l & 15, quad = l >> 4;
    const int r0 = blockIdx.x * 64;
    const float* xbase = x + (size_t)(r0 >> 12) * (CDIM * HWSZ) + (r0 & 4095);

    // ---- stage x tile: fp32 [c][row] global -> bf16 [row][c] LDS (once) ----
    {
        int cbase = (t >> 4) * 2;
        int row4  = (t & 15) * 4;
        for (int it = 0; it < 8; ++it) {
            int c = cbase + it * 32;
            float4 fa = *(const float4*)(xbase + (size_t)c * HWSZ + row4);
            float4 fb = *(const float4*)(xbase + (size_t)(c + 1) * HWSZ + row4);
            *(uint32_t*)&xs[(row4+0)*264 + c] = (uint32_t)bf16rne(fa.x) | ((uint32_t)bf16rne(fb.x) << 16);
            *(uint32_t*)&xs[(row4+1)*264 + c] = (uint32_t)bf16rne(fa.y) | ((uint32_t)bf16rne(fb.y) << 16);
            *(uint32_t*)&xs[(row4+2)*264 + c] = (uint32_t)bf16rne(fa.z) | ((uint32_t)bf16rne(fb.z) << 16);
            *(uint32_t*)&xs[(row4+3)*264 + c] = (uint32_t)bf16rne(fa.w) | ((uint32_t)bf16rne(fb.w) << 16);
        }
    }

    // preload Bq fragments for this wave's codes (16 values)
    float bqv[8][2];
    #pragma unroll
    for (int kt = 0; kt < 8; ++kt)
        #pragma unroll
        for (int cf = 0; cf < 2; ++cf)
            bqv[kt][cf] = Bq[kt*128 + w*32 + cf*16 + l15];

    __syncthreads();

    // this wave's B base: codes w*32 + cf*16 + l15, k-chunk quad*8 (16B contiguous)
    const unsigned short* bbase = cbbf + (size_t)(w*32 + l15) * CDIM + quad * 8;

    float v1[16], v2[16]; int k1[16], k2[16];
    #pragma unroll
    for (int i = 0; i < 16; ++i) { v1[i] = 3.4e38f; v2[i] = 3.4e38f; k1[i] = 0; k2[i] = 0; }

    for (int kt = 0; kt < 8; ++kt) {
        f32x4 acc[4][2];
        #pragma unroll
        for (int rf = 0; rf < 4; ++rf)
            #pragma unroll
            for (int cf = 0; cf < 2; ++cf) acc[rf][cf] = (f32x4){0.f, 0.f, 0.f, 0.f};

        #pragma unroll
        for (int step = 0; step < 8; ++step) {    // k-chunk of 32: c = step*32 + quad*8 + j
            int koff = step * 32;
            short8 bfr[2];
            #pragma unroll
            for (int cf = 0; cf < 2; ++cf)
                bfr[cf] = *(const short8*)(bbase + (size_t)(kt*128 + cf*16) * CDIM + koff);
            short8 af[4];
            #pragma unroll
            for (int rf = 0; rf < 4; ++rf)
                af[rf] = *(const short8*)&xs[(rf*16 + l15)*264 + koff + quad*8];
            #pragma unroll
            for (int rf = 0; rf < 4; ++rf)
                #pragma unroll
                for (int cf = 0; cf < 2; ++cf)
                    acc[rf][cf] = __builtin_amdgcn_mfma_f32_16x16x32_bf16(
                        af[rf], bfr[cf], acc[rf][cf], 0, 0, 0);
        }

        // epilogue: s = Bq[k] - 2*dot ; running top2 per row
        #pragma unroll
        for (int rf = 0; rf < 4; ++rf)
            #pragma unroll
            for (int reg = 0; reg < 4; ++reg) {
                int st = rf*4 + reg;
                #pragma unroll
                for (int cf = 0; cf < 2; ++cf) {
                    float s = fmaf(-2.f, acc[rf][cf][reg], bqv[kt][cf]);
                    int kk = kt*128 + w*32 + cf*16 + l15;
                    bool lt1 = s < v1[st];
                    bool lt2 = s < v2[st];
                    v2[st] = lt1 ? v1[st] : (lt2 ? s : v2[st]);
                    k2[st] = lt1 ? k1[st] : (lt2 ? kk : k2[st]);
                    v1[st] = lt1 ? s : v1[st];
                    k1[st] = lt1 ? kk : k1[st];
                }
            }
    }

    // butterfly merge across the 16 lanes (same quad, disjoint codes, same rows)
    #pragma unroll
    for (int st = 0; st < 16; ++st) {
        #pragma unroll
        for (int m = 1; m < 16; m <<= 1) {
            float ov1 = __shfl_xor(v1[st], m, 64); int on1 = __shfl_xor(k1[st], m, 64);
            float ov2 = __shfl_xor(v2[st], m, 64); int on2 = __shfl_xor(k2[st], m, 64);
            bool sw = (ov1 < v1[st]) || (ov1 == v1[st] && on1 < k1[st]);
            float wv1 = sw ? ov1 : v1[st]; int wk1 = sw ? on1 : k1[st];
            float wv2 = sw ? ov2 : v2[st]; int wk2 = sw ? on2 : k2[st];
            float lv1 = sw ? v1[st] : ov1; int lk1 = sw ? k1[st] : on1;
            bool s2 = (lv1 < wv2) || (lv1 == wv2 && lk1 < wk2);
            v1[st] = wv1; k1[st] = wk1;
            v2[st] = s2 ? lv1 : wv2;
            k2[st] = s2 ? lk1 : wk2;
        }
    }
    if (l15 == 0) {
        #pragma unroll
        for (int rf = 0; rf < 4; ++rf)
            #pragma unroll
            for (int reg = 0; reg < 4; ++reg) {
                int r = rf*16 + quad*4 + reg;
                int st = rf*4 + reg;
                sRed[w][r][0] = v1[st];
                sRed[w][r][1] = __int_as_float(k1[st]);
                sRed[w][r][2] = v2[st];
                sRed[w][r][3] = __int_as_float(k2[st]);
            }
    }
    __syncthreads();
    if (t < 64) {
        float V1 = sRed[0][t][0]; int K1 = __float_as_int(sRed[0][t][1]);
        float V2 = sRed[0][t][2]; int K2 = __float_as_int(sRed[0][t][3]);
        #pragma unroll
        for (int ww = 1; ww < 4; ++ww) {
            float b1 = sRed[ww][t][0]; int n1 = __float_as_int(sRed[ww][t][1]);
            float b2 = sRed[ww][t][2]; int n2 = __float_as_int(sRed[ww][t][3]);
            bool sw = (b1 < V1) || (b1 == V1 && n1 < K1);
            if (sw) {
                bool s2 = (V1 < b2) || (V1 == b2 && K1 < n2);
                V2 = s2 ? V1 : b2; K2 = s2 ? K1 : n2;
                V1 = b1; K1 = n1;
            } else {
                bool s2 = (b1 < V2) || (b1 == V2 && n1 < K2);
                V2 = s2 ? b1 : V2; K2 = s2 ? n1 : K2;
            }
        }
        int row = r0 + t;
        idx_out[row] = K1;
        outF[row] = (float)K1;
        if (!(V2 - V1 > DELTA)) {                 // NaN-safe: garbage -> flagged -> exact path
            int pos = atomicAdd(counter, 1);
            flag_list[pos] = row;
        }
    }
}

// ---------- exact np-fp32 rescore of flagged rows (LDS-staged codebook) ----------
// Per (row,code): single fp32 fmaf chain c=0..255 ascending; T1=A+Bq; s=T1-2*acc.
// Bit-identical values to the r2 kernel verified on all 131072 rows.
__global__ __launch_bounds__(256)
void rescore_kernel(const float* __restrict__ x, const float* __restrict__ cb,
                    const float* __restrict__ Bq,
                    const int* __restrict__ flag_list, const int* __restrict__ counter,
                    int* __restrict__ idx_out, float* __restrict__ outF) {
    __shared__ float xsh[8][264];
    __shared__ float cbs[64 * 260];     // 64 codes x 256c (+4 pad)
    __shared__ float sA[8];
    __shared__ int   rows_s[8];

    int cnt = *counter;
    int nbat = (cnt + 7) >> 3;
    for (int bat = blockIdx.x; bat < nbat; bat += gridDim.x) {
        __syncthreads();
        if (threadIdx.x < 8) {
            int j = bat * 8 + threadIdx.x;
            rows_s[threadIdx.x] = (j < cnt) ? flag_list[j] : -1;
        }
        __syncthreads();
        // stage 8 x-rows (exact fp32)
        {
            int rr = threadIdx.x >> 5;
            int c0 = (threadIdx.x & 31) * 8;
            int row = rows_s[rr]; if (row < 0) row = rows_s[0];
            const float* xr = x + (size_t)(row >> 12) * (CDIM * HWSZ) + (row & 4095);
            #pragma unroll
            for (int j = 0; j < 8; ++j)
                xsh[rr][c0 + j] = xr[(size_t)(c0 + j) * HWSZ];
        }
        __syncthreads();
        // A[r] = np.sum(x^2) via the verified numpy pairwise tree
        if (threadIdx.x < 8) {
#pragma clang fp contract(off)
            const float* xr = &xsh[threadIdx.x][0];
            float hs[2];
            for (int h = 0; h < 2; ++h) {
                float rr8[8];
                #pragma unroll
                for (int j = 0; j < 8; ++j) { float v = xr[h*128 + j]; rr8[j] = v * v; }
                for (int i = 8; i < 128; i += 8) {
                    #pragma unroll
                    for (int j = 0; j < 8; ++j) { float v = xr[h*128 + i + j]; float sq = v*v; rr8[j] = rr8[j] + sq; }
                }
                hs[h] = ((rr8[0]+rr8[1]) + (rr8[2]+rr8[3])) + ((rr8[4]+rr8[5]) + (rr8[6]+rr8[7]));
            }
            sA[threadIdx.x] = hs[0] + hs[1];
        }
        __syncthreads();

        const int r     = threadIdx.x >> 5;     // row 0..7
        const int cpair = threadIdx.x & 31;     // code slot within tile
        const float Ar  = sA[r];
        float bv = 3.4e38f; int bk = 0;

        for (int tile = 0; tile < 16; ++tile) {
            __syncthreads();
            // stage 64 codes coalesced: thread -> (code kc, 64-float segment seg)
            {
                int kc = threadIdx.x >> 2, seg = threadIdx.x & 3;
                const float* crow = cb + (size_t)(tile*64 + kc) * CDIM + seg * 64;
                float* dst = &cbs[kc * 260 + seg * 64];
                #pragma unroll
                for (int i = 0; i < 16; ++i)
                    *(float4*)&dst[i*4] = *(const float4*)&crow[i*4];
            }
            __syncthreads();
            // two exact chains per thread; kl = cpair + j*32 (bank-spread + k-ascending)
            #pragma unroll
            for (int j = 0; j < 2; ++j) {
                int kl = cpair + j * 32;
                const float* e  = &cbs[kl * 260];
                const float* xr = &xsh[r][0];
                float acc = 0.f;
                for (int c4 = 0; c4 < 64; ++c4) {
                    float4 ev = *(const float4*)&e[c4*4];
                    float4 xv = *(const float4*)&xr[c4*4];
                    acc = fmaf(xv.x, ev.x, acc);
                    acc = fmaf(xv.y, ev.y, acc);
                    acc = fmaf(xv.z, ev.z, acc);
                    acc = fmaf(xv.w, ev.w, acc);
                }
                int k = tile*64 + kl;
                float T1 = Ar + Bq[k];
                float s  = T1 - 2.0f * acc;
                if (s < bv) { bv = s; bk = k; }      // k ascending within thread
            }
        }
        // reduce across the 32 threads of each row (lanes [0..31] / [32..63] per wave)
        #pragma unroll
        for (int m = 1; m < 32; m <<= 1) {
            float ov = __shfl_xor(bv, m, 64);
            int   ok = __shfl_xor(bk, m, 64);
            if (ov < bv || (ov == bv && ok < bk)) { bv = ov; bk = ok; }
        }
        if ((threadIdx.x & 31) == 0) {
            int row = rows_s[r];
            if (row >= 0) { idx_out[row] = bk; outF[row] = (float)bk; }
        }
    }
}

// ---------- gather codebook rows + NHWC->NCHW transpose (verified r2) ----------
__global__ __launch_bounds__(256)
void gather_kernel(const float* __restrict__ cb, const int* __restrict__ idx,
                   float* __restrict__ out) {
    __shared__ int   sIdx[64];
    __shared__ float tile[64 * 129];
    const int t  = threadIdx.x;
    const int bh = blockIdx.x;
    const int b  = bh >> 6, h = bh & 63;

    if (t < 64) {
        int id = idx[bh * 64 + t];
        sIdx[t] = id;
        out[bh * 64 + t] = (float)id;
    }
    __syncthreads();

    float* qout = out + NROWS + (size_t)b * (CDIM * HWSZ) + h * 64;

    for (int c0 = 0; c0 < CDIM; c0 += 128) {
        if (c0) __syncthreads();
        {
            int ww = t >> 2, seg = t & 3;
            const float* crow = cb + (size_t)sIdx[ww] * CDIM + c0;
            #pragma unroll
            for (int jj = 0; jj < 8; ++jj) {
                int f = seg + 4 * jj;
                float4 v = *(const float4*)(crow + 4 * f);
                float* dst = &tile[ww * 129 + 4 * f];
                dst[0] = v.x; dst[1] = v.y; dst[2] = v.z; dst[3] = v.w;
            }
        }
        __syncthreads();
        {
            int g = t >> 4, w4 = (t & 15) * 4;
            #pragma unroll
            for (int it = 0; it < 8; ++it) {
                int cl = it * 16 + g;
                float4 v;
                v.x = tile[(w4 + 0) * 129 + cl];
                v.y = tile[(w4 + 1) * 129 + cl];
                v.z = tile[(w4 + 2) * 129 + cl];
                v.w = tile[(w4 + 3) * 129 + cl];
                *(float4*)(qout + (size_t)(c0 + cl) * HWSZ + w4) = v;
            }
        }
    }
}

extern "C" void kernel_launch(void* const* d_in, const int* in_sizes, int n_in,
                              void* d_out, int out_size, void* d_ws, size_t ws_size,
                              hipStream_t stream) {
    const float* x  = (const float*)d_in[0];
    const float* cb = (const float*)d_in[1];
    char* ws = (char*)d_ws;
    float*          Bq    = (float*)(ws + WS_BQ);
    int*            idxbf = (int*)(ws + WS_IDX);
    unsigned short* cbbf  = (unsigned short*)(ws + WS_CBBF);
    int*            cnt   = (int*)(ws + WS_CNT);
    int*            list  = (int*)(ws + WS_LIST);
    float*          out   = (float*)d_out;

    codesq_kernel<<<KCODES / 256, 256, 0, stream>>>(cb, Bq);
    cbcvt_kernel <<<256, 256, 0, stream>>>(cb, cbbf, cnt);
    screen_kernel<<<NROWS / 64, 256, 0, stream>>>(x, cbbf, Bq, idxbf, out, list, cnt);
    rescore_kernel<<<2048, 256, 0, stream>>>(x, cb, Bq, list, cnt, idxbf, out);
    gather_kernel<<<32 * 64, 256, 0, stream>>>(cb, idxbf, out);
}